// Round 1
// baseline (6457.480 us; speedup 1.0000x reference)
//
#include <hip/hip_runtime.h>

#define CIN  120
#define NCO  24
#define SDIM 48
#define SS   (SDIM*SDIM)
#define SSS  (SDIM*SDIM*SDIM)
#define WCO  15000   // co stride in w_gate (= 120*5*5*5)

__global__ __launch_bounds__(128)
void gated_act_fused(const float* __restrict__ x,
                     const float* __restrict__ w,
                     float* __restrict__ out)
{
    const int gid = blockIdx.x * 128 + threadIdx.x;
    const int b = gid / SSS;
    const int s = gid - b * SSS;
    const int oz = s % SDIM;
    const int t2 = s / SDIM;
    const int oy = t2 % SDIM;
    const int ox = t2 / SDIM;

    const float* __restrict__ xb = x + (size_t)b * CIN * SSS;

    float acc[NCO];
#pragma unroll
    for (int i = 0; i < NCO; ++i) acc[i] = 0.f;

    // z-window validity + clamped indices (loop-invariant per thread)
    int izc[5];
    bool okz[5];
#pragma unroll
    for (int dz = 0; dz < 5; ++dz) {
        int iz = oz + dz - 2;
        okz[dz] = (unsigned)iz < (unsigned)SDIM;
        izc[dz] = okz[dz] ? iz : 0;
    }

    for (int ci = 0; ci < CIN; ++ci) {
        const float* __restrict__ xc = xb + (size_t)ci * SSS;
        const float* __restrict__ wc = w + ci * 125;
#pragma unroll 1
        for (int dx = 0; dx < 5; ++dx) {
            const int ix = ox + dx - 2;
            const bool okx = (unsigned)ix < (unsigned)SDIM;
            const int ixc = okx ? ix : 0;
#pragma unroll 1
            for (int dy = 0; dy < 5; ++dy) {
                const int iy = oy + dy - 2;
                const bool oky = (unsigned)iy < (unsigned)SDIM;
                const int iyc = oky ? iy : 0;
                const bool okxy = okx && oky;
                const float* __restrict__ xrow = xc + ixc * SS + iyc * SDIM;

                float xv[5];
#pragma unroll
                for (int dz = 0; dz < 5; ++dz) {
                    float v = xrow[izc[dz]];
                    xv[dz] = (okxy && okz[dz]) ? v : 0.f;
                }

                // wave-uniform weight address -> scalar loads
                const float* __restrict__ wrow = wc + dx * 25 + dy * 5;
#pragma unroll
                for (int dz = 0; dz < 5; ++dz) {
                    const float v = xv[dz];
#pragma unroll
                    for (int co = 0; co < NCO; ++co)
                        acc[co] = fmaf(v, wrow[co * WCO + dz], acc[co]);
                }
            }
        }
    }

    // sigmoid gates
    float g[NCO];
#pragma unroll
    for (int co = 0; co < NCO; ++co)
        g[co] = 1.f / (1.f + __expf(-acc[co]));

    float* __restrict__ ob = out + (size_t)b * CIN * SSS + s;
    const float* __restrict__ xs = xb + s;

    // l=0: relu, channels 0..31
#pragma unroll
    for (int c = 0; c < 32; ++c) {
        float v = xs[(size_t)c * SSS];
        ob[(size_t)c * SSS] = v > 0.f ? v : 0.f;
    }
    // l=1: mul=16, dim=3, channels 32..79, gates g[0..15]
#pragma unroll
    for (int m = 0; m < 16; ++m) {
        const float gv = g[m];
#pragma unroll
        for (int k = 0; k < 3; ++k) {
            const int c = 32 + m * 3 + k;
            ob[(size_t)c * SSS] = xs[(size_t)c * SSS] * gv;
        }
    }
    // l=2: mul=8, dim=5, channels 80..119, gates g[16..23]
#pragma unroll
    for (int m = 0; m < 8; ++m) {
        const float gv = g[16 + m];
#pragma unroll
        for (int k = 0; k < 5; ++k) {
            const int c = 80 + m * 5 + k;
            ob[(size_t)c * SSS] = xs[(size_t)c * SSS] * gv;
        }
    }
}

extern "C" void kernel_launch(void* const* d_in, const int* in_sizes, int n_in,
                              void* d_out, int out_size, void* d_ws, size_t ws_size,
                              hipStream_t stream)
{
    const float* x = (const float*)d_in[0];
    const float* w = (const float*)d_in[1];
    float* out = (float*)d_out;

    const int total_threads = 2 * SSS;          // one thread per (b, spatial point)
    dim3 grid(total_threads / 128), block(128); // 221184/128 = 1728 blocks, exact
    hipLaunchKernelGGL(gated_act_fused, grid, block, 0, stream, x, w, out);
}

// Round 2
// 4422.512 us; speedup vs baseline: 1.4601x; 1.4601x over previous
//
#include <hip/hip_runtime.h>

#define CIN  120
#define NCO  24
#define SDIM 48
#define SS   (SDIM*SDIM)
#define SSS  (SDIM*SDIM*SDIM)
#define NTAP 125
#define WTOT (NCO*CIN*NTAP)   // 360000 floats = 1.44 MB

// w[co][ci*125 + tap]  ->  wp[(ci*125 + tap)*24 + co]
__global__ __launch_bounds__(256)
void repack_w(const float* __restrict__ w, float* __restrict__ wp)
{
    int idx = blockIdx.x * 256 + threadIdx.x;
    if (idx >= WTOT) return;
    int co = idx % NCO;
    int t  = idx / NCO;
    wp[idx] = w[co * (CIN * NTAP) + t];
}

__global__ __launch_bounds__(128)
void gated_act(const float* __restrict__ x,
               const float* __restrict__ wp,
               float* __restrict__ out)
{
    const int gid = blockIdx.x * 128 + threadIdx.x;
    const int oz = gid % SDIM;
    int r = gid / SDIM;
    const int oy = r % SDIM; r /= SDIM;
    const int ox = r % SDIM;
    const int b  = r / SDIM;

    const float* __restrict__ xb = x + (size_t)b * CIN * SSS;

    float acc[NCO];
#pragma unroll
    for (int i = 0; i < NCO; ++i) acc[i] = 0.f;

    int izc[5]; bool okz[5];
#pragma unroll
    for (int dz = 0; dz < 5; ++dz) {
        int iz = oz + dz - 2;
        okz[dz] = (unsigned)iz < (unsigned)SDIM;
        izc[dz] = okz[dz] ? iz : 0;
    }

    for (int ci = 0; ci < CIN; ++ci) {
        const float* __restrict__ xc = xb + (size_t)ci * SSS;
        const float* __restrict__ wc = wp + ci * (NTAP * NCO);
#pragma unroll 1
        for (int dx = 0; dx < 5; ++dx) {
            const int ix = ox + dx - 2;
            const bool okx = (unsigned)ix < (unsigned)SDIM;
            const int ixc = okx ? ix : 0;
#pragma unroll 1
            for (int dy = 0; dy < 5; ++dy) {
                const int iy = oy + dy - 2;
                const bool oky = (unsigned)iy < (unsigned)SDIM;
                const int iyc = oky ? iy : 0;
                const bool okxy = okx && oky;
                const float* __restrict__ xrow = xc + ixc * SS + iyc * SDIM;

                float xv[5];
#pragma unroll
                for (int dz = 0; dz < 5; ++dz) {
                    float v = xrow[izc[dz]];
                    xv[dz] = (okxy && okz[dz]) ? v : 0.f;
                }

                // contiguous, wave-uniform weight block: 120 floats = 8
                // sequential 64B scalar-cache lines -> s_load_dwordxN merges
                const float* __restrict__ wr = wc + (dx * 25 + dy * 5) * NCO;
#pragma unroll
                for (int dz = 0; dz < 5; ++dz) {
                    const float v = xv[dz];
#pragma unroll
                    for (int co = 0; co < NCO; ++co)
                        acc[co] = fmaf(v, wr[dz * NCO + co], acc[co]);
                }
            }
        }
    }

    // sigmoid gates
    float g[NCO];
#pragma unroll
    for (int co = 0; co < NCO; ++co)
        g[co] = 1.f / (1.f + __expf(-acc[co]));

    const size_t sbase = (size_t)b * CIN * SSS + ox * SS + oy * SDIM + oz;
    float* __restrict__ ob = out + sbase;
    const float* __restrict__ xs = x + sbase;

    // l=0: relu, channels 0..31
#pragma unroll
    for (int c = 0; c < 32; ++c) {
        float v = xs[(size_t)c * SSS];
        ob[(size_t)c * SSS] = v > 0.f ? v : 0.f;
    }
    // l=1: mul=16, dim=3, channels 32..79, gates g[0..15]
#pragma unroll
    for (int m = 0; m < 16; ++m) {
        const float gv = g[m];
#pragma unroll
        for (int k = 0; k < 3; ++k) {
            const int c = 32 + m * 3 + k;
            ob[(size_t)c * SSS] = xs[(size_t)c * SSS] * gv;
        }
    }
    // l=2: mul=8, dim=5, channels 80..119, gates g[16..23]
#pragma unroll
    for (int m = 0; m < 8; ++m) {
        const float gv = g[16 + m];
#pragma unroll
        for (int k = 0; k < 5; ++k) {
            const int c = 80 + m * 5 + k;
            ob[(size_t)c * SSS] = xs[(size_t)c * SSS] * gv;
        }
    }
}

extern "C" void kernel_launch(void* const* d_in, const int* in_sizes, int n_in,
                              void* d_out, int out_size, void* d_ws, size_t ws_size,
                              hipStream_t stream)
{
    const float* x = (const float*)d_in[0];
    const float* w = (const float*)d_in[1];
    float* out = (float*)d_out;
    float* wp  = (float*)d_ws;   // 1.44 MB repacked weights

    hipLaunchKernelGGL(repack_w, dim3((WTOT + 255) / 256), dim3(256), 0, stream, w, wp);

    const int total_threads = 2 * SSS;
    hipLaunchKernelGGL(gated_act, dim3(total_threads / 128), dim3(128), 0, stream,
                       x, wp, out);
}

// Round 3
// 1972.600 us; speedup vs baseline: 3.2736x; 2.2420x over previous
//
#include <hip/hip_runtime.h>

typedef __attribute__((ext_vector_type(8))) short short8;
typedef __attribute__((ext_vector_type(4))) float f32x4;

#define SDIM 48
#define SS   (48*48)
#define SSS  (48*48*48)
#define CIN  120
#define CIP  128
#define NCO  24
#define ZP   52
#define NTAP 125

// ws layout: [0, WP_BYTES) bf16 weights; [WP_BYTES, +XT_BYTES) bf16 transposed x
#define WP_USHORTS (4*25*5*32*32)              // 512000
#define WP_BYTES   ((size_t)WP_USHORTS*2)      // 1,024,000
#define XT_USHORTS ((size_t)2*48*48*ZP*CIP)    // 30,670,848
#define XT_BYTES   (XT_USHORTS*2)
#define WTOT_F32   (NCO*CIN*NTAP)              // fallback fp32 repack: 360000 floats

__device__ __forceinline__ unsigned short f2bf(float f){
    unsigned u = __float_as_uint(f);
    u = (u + 0x7FFFu + ((u >> 16) & 1u)) >> 16;
    return (unsigned short)u;
}

// ---------------- MFMA path ----------------

// x[b][ci][X][Y][Z] f32 -> xt[b][ix][iy][zp][ci] bf16, zp = z+2 (z halo), ci pad to 128
__global__ __launch_bounds__(128)
void transpose_x(const float* __restrict__ x, unsigned short* __restrict__ xt)
{
    const int ci = threadIdx.x;            // 0..127
    int bid = blockIdx.x;                  // (b*48 + ix)*48 + iy
    const int iy = bid % 48; bid /= 48;
    const int ix = bid % 48;
    const int b  = bid / 48;
    const bool cok = ci < CIN;
    const float* __restrict__ src = x + (((size_t)(b*CIN + (cok?ci:0))*48 + ix)*48 + iy)*48;
    unsigned short* __restrict__ dst = xt + (((size_t)(b*48 + ix)*48 + iy)*ZP)*CIP + ci;
    for (int zp = 0; zp < ZP; ++zp) {
        int z = zp - 2;
        float v = (cok && (unsigned)z < 48u) ? src[z] : 0.f;
        dst[(size_t)zp*CIP] = f2bf(v);
    }
}

// w[co][ci][dx][dy][dz] f32 -> wp[cc][t=dx*5+dy][dz][co 32][cik 32] bf16 (zero-padded)
__global__ __launch_bounds__(256)
void repack_w_bf16(const float* __restrict__ w, unsigned short* __restrict__ wp)
{
    int idx = blockIdx.x*256 + threadIdx.x;
    if (idx >= WP_USHORTS) return;
    int cik = idx & 31;
    int co  = (idx >> 5) & 31;
    int dz  = (idx >> 10) % 5;
    int t   = (idx / 5120) % 25;
    int cc  = idx / 128000;
    int ci  = cc*32 + cik;
    float v = 0.f;
    if (co < NCO && ci < CIN)
        v = w[(size_t)(co*CIN + ci)*NTAP + t*5 + dz];
    wp[idx] = f2bf(v);
}

__global__ __launch_bounds__(512)
void conv_mfma(const unsigned short* __restrict__ xt,
               const unsigned short* __restrict__ wp,
               const float* __restrict__ x,
               float* __restrict__ out)
{
    __shared__ __align__(16) unsigned short wl[5*32*32];   // 10,240 B
    __shared__ float gl[192*NCO];                          // 18,432 B

    int bid = blockIdx.x;
    const int oyq = bid % 12; bid /= 12;
    const int ox = bid % 48;
    const int b  = bid / 48;

    const int tid = threadIdx.x;
    const int wave = tid >> 6, lane = tid & 63;
    const int oyl = wave >> 1, ntile = wave & 1;   // wave = (oy-line, co-half)
    const int oy  = oyq*4 + oyl;
    const int l15 = lane & 15, l4 = lane >> 4;

    f32x4 acc0 = {0,0,0,0}, acc1 = {0,0,0,0}, acc2 = {0,0,0,0};

    for (int cc = 0; cc < 4; ++cc) {
      for (int t = 0; t < 25; ++t) {
        __syncthreads();
        {   // stage 10,240B = 640 x short8 with 512 threads
            const short8* s = (const short8*)(wp + (size_t)(cc*25 + t)*5120);
            short8* d = (short8*)wl;
            d[tid] = s[tid];
            if (tid < 128) d[512 + tid] = s[512 + tid];
        }
        __syncthreads();
        const int dx = t / 5, dy = t % 5;
        const int ix = ox + dx - 2, iy = oy + dy - 2;
        if ((unsigned)ix < 48u && (unsigned)iy < 48u) {
            // A: x rows zp = z_out + dz, 8 contiguous ci per lane (row = lane&15)
            const unsigned short* xb = xt + (((size_t)(b*48 + ix)*48 + iy)*ZP)*CIP
                                          + cc*32 + l4*8;
            // B: w_lds[dz][co][cik], col = lane&15 -> co, 8 contiguous cik per lane
            const unsigned short* wb = wl + (ntile*16 + l15)*32 + l4*8;
#pragma unroll
            for (int dz = 0; dz < 5; ++dz) {
                short8 bf = *(const short8*)(wb + dz*1024);
                short8 a0 = *(const short8*)(xb + (size_t)(l15 + dz)*CIP);
                acc0 = __builtin_amdgcn_mfma_f32_16x16x32_bf16(a0, bf, acc0, 0, 0, 0);
                short8 a1 = *(const short8*)(xb + (size_t)(16 + l15 + dz)*CIP);
                acc1 = __builtin_amdgcn_mfma_f32_16x16x32_bf16(a1, bf, acc1, 0, 0, 0);
                short8 a2 = *(const short8*)(xb + (size_t)(32 + l15 + dz)*CIP);
                acc2 = __builtin_amdgcn_mfma_f32_16x16x32_bf16(a2, bf, acc2, 0, 0, 0);
            }
        }
      }
    }

    // C/D layout (m89-verified): col = lane&15 (co), row = (lane>>4)*4 + r (z)
    const int co = ntile*16 + l15;
    if (co < NCO) {
#pragma unroll
        for (int r = 0; r < 4; ++r) {
            int z0 = l4*4 + r;
            gl[(oyl*48 + z0     )*NCO + co] = 1.f / (1.f + __expf(-acc0[r]));
            gl[(oyl*48 + z0 + 16)*NCO + co] = 1.f / (1.f + __expf(-acc1[r]));
            gl[(oyl*48 + z0 + 32)*NCO + co] = 1.f / (1.f + __expf(-acc2[r]));
        }
    }
    __syncthreads();

    // epilogue: 384 threads, each (point, channel-half); x re-read in fp32
    if (tid < 384) {
        const int p = tid % 192;           // = oyl2*48 + z
        const int half = tid / 192;
        const int z = p % 48, oyl2 = p / 48;
        const int oy2 = oyq*4 + oyl2;
        const size_t sp = ((size_t)ox*48 + oy2)*48 + z;
        const float* __restrict__ xsp = x   + (size_t)b*CIN*SSS + sp;
        float*       __restrict__ osp = out + (size_t)b*CIN*SSS + sp;
        const float* __restrict__ gp = gl + p*NCO;
        for (int c = half*60; c < half*60 + 60; ++c) {
            float v = xsp[(size_t)c*SSS];
            float o;
            if (c < 32)       o = v > 0.f ? v : 0.f;
            else if (c < 80)  o = v * gp[(c - 32) / 3];
            else              o = v * gp[16 + (c - 80) / 5];
            osp[(size_t)c*SSS] = o;
        }
    }
}

// ---------------- fallback paths (verified rounds 1-2) ----------------

__global__ __launch_bounds__(256)
void repack_w_f32(const float* __restrict__ w, float* __restrict__ wpf)
{
    int idx = blockIdx.x * 256 + threadIdx.x;
    if (idx >= WTOT_F32) return;
    int co = idx % NCO;
    int t  = idx / NCO;
    wpf[idx] = w[co * (CIN * NTAP) + t];
}

__global__ __launch_bounds__(128)
void gated_act_f32(const float* __restrict__ x,
                   const float* __restrict__ wpf,
                   float* __restrict__ out)
{
    const int gid = blockIdx.x * 128 + threadIdx.x;
    const int oz = gid % SDIM;
    int r = gid / SDIM;
    const int oy = r % SDIM; r /= SDIM;
    const int ox = r % SDIM;
    const int b  = r / SDIM;

    const float* __restrict__ xb = x + (size_t)b * CIN * SSS;
    float acc[NCO];
#pragma unroll
    for (int i = 0; i < NCO; ++i) acc[i] = 0.f;

    int izc[5]; bool okz[5];
#pragma unroll
    for (int dz = 0; dz < 5; ++dz) {
        int iz = oz + dz - 2;
        okz[dz] = (unsigned)iz < (unsigned)SDIM;
        izc[dz] = okz[dz] ? iz : 0;
    }
    for (int ci = 0; ci < CIN; ++ci) {
        const float* __restrict__ xc = xb + (size_t)ci * SSS;
        const float* __restrict__ wc = wpf + ci * (NTAP * NCO);
#pragma unroll 1
        for (int dx = 0; dx < 5; ++dx) {
            const int ix = ox + dx - 2;
            const bool okx = (unsigned)ix < (unsigned)SDIM;
            const int ixc = okx ? ix : 0;
#pragma unroll 1
            for (int dy = 0; dy < 5; ++dy) {
                const int iy = oy + dy - 2;
                const bool oky = (unsigned)iy < (unsigned)SDIM;
                const int iyc = oky ? iy : 0;
                const bool okxy = okx && oky;
                const float* __restrict__ xrow = xc + ixc * SS + iyc * SDIM;
                float xv[5];
#pragma unroll
                for (int dz = 0; dz < 5; ++dz) {
                    float v = xrow[izc[dz]];
                    xv[dz] = (okxy && okz[dz]) ? v : 0.f;
                }
                const float* __restrict__ wr = wc + (dx * 25 + dy * 5) * NCO;
#pragma unroll
                for (int dz = 0; dz < 5; ++dz) {
                    const float v = xv[dz];
#pragma unroll
                    for (int co = 0; co < NCO; ++co)
                        acc[co] = fmaf(v, wr[dz * NCO + co], acc[co]);
                }
            }
        }
    }
    float g[NCO];
#pragma unroll
    for (int co = 0; co < NCO; ++co)
        g[co] = 1.f / (1.f + __expf(-acc[co]));

    const size_t sbase = (size_t)b * CIN * SSS + ox * SS + oy * SDIM + oz;
    float* __restrict__ ob = out + sbase;
    const float* __restrict__ xs = x + sbase;
#pragma unroll
    for (int c = 0; c < 32; ++c) {
        float v = xs[(size_t)c * SSS];
        ob[(size_t)c * SSS] = v > 0.f ? v : 0.f;
    }
#pragma unroll
    for (int m = 0; m < 16; ++m) {
        const float gv = g[m];
#pragma unroll
        for (int k = 0; k < 3; ++k) {
            const int c = 32 + m * 3 + k;
            ob[(size_t)c * SSS] = xs[(size_t)c * SSS] * gv;
        }
    }
#pragma unroll
    for (int m = 0; m < 8; ++m) {
        const float gv = g[16 + m];
#pragma unroll
        for (int k = 0; k < 5; ++k) {
            const int c = 80 + m * 5 + k;
            ob[(size_t)c * SSS] = xs[(size_t)c * SSS] * gv;
        }
    }
}

extern "C" void kernel_launch(void* const* d_in, const int* in_sizes, int n_in,
                              void* d_out, int out_size, void* d_ws, size_t ws_size,
                              hipStream_t stream)
{
    const float* x = (const float*)d_in[0];
    const float* w = (const float*)d_in[1];
    float* out = (float*)d_out;

    if (ws_size >= WP_BYTES + XT_BYTES) {
        unsigned short* wp  = (unsigned short*)d_ws;
        unsigned short* xtb = (unsigned short*)((char*)d_ws + WP_BYTES);
        hipLaunchKernelGGL(repack_w_bf16, dim3((WP_USHORTS + 255) / 256), dim3(256),
                           0, stream, w, wp);
        hipLaunchKernelGGL(transpose_x, dim3(2*48*48), dim3(128), 0, stream, x, xtb);
        hipLaunchKernelGGL(conv_mfma, dim3(2*48*12), dim3(512), 0, stream,
                           xtb, wp, x, out);
    } else if (ws_size >= (size_t)WTOT_F32 * 4) {
        float* wpf = (float*)d_ws;
        hipLaunchKernelGGL(repack_w_f32, dim3((WTOT_F32 + 255) / 256), dim3(256),
                           0, stream, w, wpf);
        hipLaunchKernelGGL(gated_act_f32, dim3(2*SSS/128), dim3(128), 0, stream,
                           x, wpf, out);
    }
}

// Round 4
// 1415.692 us; speedup vs baseline: 4.5614x; 1.3934x over previous
//
#include <hip/hip_runtime.h>

typedef __attribute__((ext_vector_type(8))) short short8;
typedef __attribute__((ext_vector_type(4))) float f32x4;

#define SDIM 48
#define SS   (48*48)
#define SSS  (48*48*48)
#define CIN  120
#define CIP  128
#define NCO  24
#define ZP   52
#define NTAP 125

#define WP_USHORTS (4*25*5*32*32)              // 512000
#define WP_BYTES   ((size_t)WP_USHORTS*2)
#define XT_USHORTS ((size_t)2*48*48*ZP*CIP)
#define XT_BYTES   (XT_USHORTS*2)
#define WTOT_F32   (NCO*CIN*NTAP)

__device__ __forceinline__ unsigned short f2bf(float f){
    unsigned u = __float_as_uint(f);
    u = (u + 0x7FFFu + ((u >> 16) & 1u)) >> 16;
    return (unsigned short)u;
}

// ---------------- MFMA path ----------------

// x[b][ci][X][Y][Z] f32 -> xt[b][ix][iy][zp][ci] bf16, zp = z+2 halo, ci pad 128
__global__ __launch_bounds__(128)
void transpose_x(const float* __restrict__ x, unsigned short* __restrict__ xt)
{
    const int ci = threadIdx.x;
    int bid = blockIdx.x;
    const int iy = bid % 48; bid /= 48;
    const int ix = bid % 48;
    const int b  = bid / 48;
    const bool cok = ci < CIN;
    const float* __restrict__ src = x + (((size_t)(b*CIN + (cok?ci:0))*48 + ix)*48 + iy)*48;
    unsigned short* __restrict__ dst = xt + (((size_t)(b*48 + ix)*48 + iy)*ZP)*CIP + ci;
    for (int zp = 0; zp < ZP; ++zp) {
        int z = zp - 2;
        float v = (cok && (unsigned)z < 48u) ? src[z] : 0.f;
        dst[(size_t)zp*CIP] = f2bf(v);
    }
}

// w[co][ci][dx][dy][dz] f32 -> wp[cc][t][dz][co 32][cik 32] bf16 (zero-padded)
__global__ __launch_bounds__(256)
void repack_w_bf16(const float* __restrict__ w, unsigned short* __restrict__ wp)
{
    int idx = blockIdx.x*256 + threadIdx.x;
    if (idx >= WP_USHORTS) return;
    int cik = idx & 31;
    int co  = (idx >> 5) & 31;
    int dz  = (idx >> 10) % 5;
    int t   = (idx / 5120) % 25;
    int cc  = idx / 128000;
    int ci  = cc*32 + cik;
    float v = 0.f;
    if (co < NCO && ci < CIN)
        v = w[(size_t)(co*CIN + ci)*NTAP + t*5 + dz];
    wp[idx] = f2bf(v);
}

#define MFMA16(a,b,c) __builtin_amdgcn_mfma_f32_16x16x32_bf16(a,b,c,0,0,0)

__global__ __launch_bounds__(256)
void conv_mfma(const unsigned short* __restrict__ xt,
               const unsigned short* __restrict__ wp,
               const float* __restrict__ x,
               float* __restrict__ out)
{
    __shared__ float gl[192*NCO];   // 18,432 B

    // bijective XCD swizzle: 1152 blocks = 8 XCDs x 144 contiguous logical ids
    int bid = (blockIdx.x & 7) * 144 + (blockIdx.x >> 3);
    const int oyq = bid % 12; bid /= 12;
    const int ox = bid % 48;
    const int b  = bid / 48;

    const int tid = threadIdx.x;
    const int wave = tid >> 6, lane = tid & 63;
    const int oy  = oyq*4 + wave;             // wave = one oy line, N=32 co
    const int l15 = lane & 15, l4 = lane >> 4;

    f32x4 acc00={0,0,0,0}, acc01={0,0,0,0};
    f32x4 acc10={0,0,0,0}, acc11={0,0,0,0};
    f32x4 acc20={0,0,0,0}, acc21={0,0,0,0};

    const size_t rowbase = ((size_t)(b*48 + ox)*48 + oy)*ZP;   // at dx=2,dy=2

    for (int cc = 0; cc < 4; ++cc) {
      const unsigned short* __restrict__ xcc = xt + cc*32 + l4*8;
      const unsigned short* __restrict__ wcc = wp + (size_t)cc*25*5120 + l15*32 + l4*8;
#pragma unroll 1
      for (int t = 0; t < 25; ++t) {
        const int dx = t/5, dy = t%5;
        const int ix = ox + dx - 2, iy = oy + dy - 2;
        if ((unsigned)ix >= 48u || (unsigned)iy >= 48u) continue;  // wave-uniform
        const unsigned short* __restrict__ xb =
            xcc + (rowbase + ((size_t)(dx-2)*48 + (dy-2))*ZP)*CIP;
        const unsigned short* __restrict__ wb = wcc + (size_t)t*5120;
#pragma unroll
        for (int dz = 0; dz < 5; ++dz) {
            short8 b0 = *(const short8*)(wb + dz*1024);
            short8 b1 = *(const short8*)(wb + dz*1024 + 512);
            short8 a0 = *(const short8*)(xb + (size_t)(l15 + dz)*CIP);
            short8 a1 = *(const short8*)(xb + (size_t)(16 + l15 + dz)*CIP);
            short8 a2 = *(const short8*)(xb + (size_t)(32 + l15 + dz)*CIP);
            acc00 = MFMA16(a0, b0, acc00);  acc01 = MFMA16(a0, b1, acc01);
            acc10 = MFMA16(a1, b0, acc10);  acc11 = MFMA16(a1, b1, acc11);
            acc20 = MFMA16(a2, b0, acc20);  acc21 = MFMA16(a2, b1, acc21);
        }
      }
    }

    // C/D: col = lane&15 (co within tile), row = (lane>>4)*4 + r (z within 16)
#pragma unroll
    for (int nt = 0; nt < 2; ++nt) {
        const int co = nt*16 + l15;
        if (co < NCO) {
            const f32x4 a0 = nt ? acc01 : acc00;
            const f32x4 a1 = nt ? acc11 : acc10;
            const f32x4 a2 = nt ? acc21 : acc20;
#pragma unroll
            for (int r = 0; r < 4; ++r) {
                int z0 = l4*4 + r;
                gl[(wave*48 + z0     )*NCO + co] = 1.f / (1.f + __expf(-a0[r]));
                gl[(wave*48 + z0 + 16)*NCO + co] = 1.f / (1.f + __expf(-a1[r]));
                gl[(wave*48 + z0 + 32)*NCO + co] = 1.f / (1.f + __expf(-a2[r]));
            }
        }
    }
    __syncthreads();

    // epilogue: 384 work items = (point 192) x (channel-half 2), fp32 x re-read
    for (int i = tid; i < 384; i += 256) {
        const int p = i % 192;
        const int half = i / 192;
        const int z = p % 48, oyl = p / 48;
        const int oy2 = oyq*4 + oyl;
        const size_t sp = ((size_t)ox*48 + oy2)*48 + z;
        const float* __restrict__ xsp = x   + (size_t)b*CIN*SSS + sp;
        float*       __restrict__ osp = out + (size_t)b*CIN*SSS + sp;
        const float* __restrict__ gp = gl + p*NCO;
        for (int c = half*60; c < half*60 + 60; ++c) {
            float v = xsp[(size_t)c*SSS];
            float o;
            if (c < 32)       o = v > 0.f ? v : 0.f;
            else if (c < 80)  o = v * gp[(c - 32) / 3];
            else              o = v * gp[16 + (c - 80) / 5];
            osp[(size_t)c*SSS] = o;
        }
    }
}

// ---------------- fallback paths (verified rounds 1-2) ----------------

__global__ __launch_bounds__(256)
void repack_w_f32(const float* __restrict__ w, float* __restrict__ wpf)
{
    int idx = blockIdx.x * 256 + threadIdx.x;
    if (idx >= WTOT_F32) return;
    int co = idx % NCO;
    int t  = idx / NCO;
    wpf[idx] = w[co * (CIN * NTAP) + t];
}

__global__ __launch_bounds__(128)
void gated_act_f32(const float* __restrict__ x,
                   const float* __restrict__ wpf,
                   float* __restrict__ out)
{
    const int gid = blockIdx.x * 128 + threadIdx.x;
    const int oz = gid % SDIM;
    int r = gid / SDIM;
    const int oy = r % SDIM; r /= SDIM;
    const int ox = r % SDIM;
    const int b  = r / SDIM;

    const float* __restrict__ xb = x + (size_t)b * CIN * SSS;
    float acc[NCO];
#pragma unroll
    for (int i = 0; i < NCO; ++i) acc[i] = 0.f;

    int izc[5]; bool okz[5];
#pragma unroll
    for (int dz = 0; dz < 5; ++dz) {
        int iz = oz + dz - 2;
        okz[dz] = (unsigned)iz < (unsigned)SDIM;
        izc[dz] = okz[dz] ? iz : 0;
    }
    for (int ci = 0; ci < CIN; ++ci) {
        const float* __restrict__ xc = xb + (size_t)ci * SSS;
        const float* __restrict__ wc = wpf + ci * (NTAP * NCO);
#pragma unroll 1
        for (int dx = 0; dx < 5; ++dx) {
            const int ix = ox + dx - 2;
            const bool okx = (unsigned)ix < (unsigned)SDIM;
            const int ixc = okx ? ix : 0;
#pragma unroll 1
            for (int dy = 0; dy < 5; ++dy) {
                const int iy = oy + dy - 2;
                const bool oky = (unsigned)iy < (unsigned)SDIM;
                const int iyc = oky ? iy : 0;
                const bool okxy = okx && oky;
                const float* __restrict__ xrow = xc + ixc * SS + iyc * SDIM;
                float xv[5];
#pragma unroll
                for (int dz = 0; dz < 5; ++dz) {
                    float v = xrow[izc[dz]];
                    xv[dz] = (okxy && okz[dz]) ? v : 0.f;
                }
                const float* __restrict__ wr = wc + (dx * 25 + dy * 5) * NCO;
#pragma unroll
                for (int dz = 0; dz < 5; ++dz) {
                    const float v = xv[dz];
#pragma unroll
                    for (int co = 0; co < NCO; ++co)
                        acc[co] = fmaf(v, wr[dz * NCO + co], acc[co]);
                }
            }
        }
    }
    float g[NCO];
#pragma unroll
    for (int co = 0; co < NCO; ++co)
        g[co] = 1.f / (1.f + __expf(-acc[co]));

    const size_t sbase = (size_t)b * CIN * SSS + ox * SS + oy * SDIM + oz;
    float* __restrict__ ob = out + sbase;
    const float* __restrict__ xs = x + sbase;
#pragma unroll
    for (int c = 0; c < 32; ++c) {
        float v = xs[(size_t)c * SSS];
        ob[(size_t)c * SSS] = v > 0.f ? v : 0.f;
    }
#pragma unroll
    for (int m = 0; m < 16; ++m) {
        const float gv = g[m];
#pragma unroll
        for (int k = 0; k < 3; ++k) {
            const int c = 32 + m * 3 + k;
            ob[(size_t)c * SSS] = xs[(size_t)c * SSS] * gv;
        }
    }
#pragma unroll
    for (int m = 0; m < 8; ++m) {
        const float gv = g[16 + m];
#pragma unroll
        for (int k = 0; k < 5; ++k) {
            const int c = 80 + m * 5 + k;
            ob[(size_t)c * SSS] = xs[(size_t)c * SSS] * gv;
        }
    }
}

extern "C" void kernel_launch(void* const* d_in, const int* in_sizes, int n_in,
                              void* d_out, int out_size, void* d_ws, size_t ws_size,
                              hipStream_t stream)
{
    const float* x = (const float*)d_in[0];
    const float* w = (const float*)d_in[1];
    float* out = (float*)d_out;

    if (ws_size >= WP_BYTES + XT_BYTES) {
        unsigned short* wp  = (unsigned short*)d_ws;
        unsigned short* xtb = (unsigned short*)((char*)d_ws + WP_BYTES);
        hipLaunchKernelGGL(repack_w_bf16, dim3((WP_USHORTS + 255) / 256), dim3(256),
                           0, stream, w, wp);
        hipLaunchKernelGGL(transpose_x, dim3(2*48*48), dim3(128), 0, stream, x, xtb);
        hipLaunchKernelGGL(conv_mfma, dim3(2*48*12), dim3(256), 0, stream,
                           xtb, wp, x, out);
    } else if (ws_size >= (size_t)WTOT_F32 * 4) {
        float* wpf = (float*)d_ws;
        hipLaunchKernelGGL(repack_w_f32, dim3((WTOT_F32 + 255) / 256), dim3(256),
                           0, stream, w, wpf);
        hipLaunchKernelGGL(gated_act_f32, dim3(2*SSS/128), dim3(128), 0, stream,
                           x, wpf, out);
    }
}

// Round 5
// 484.360 us; speedup vs baseline: 13.3320x; 2.9228x over previous
//
#include <hip/hip_runtime.h>

typedef __attribute__((ext_vector_type(8))) short short8;
typedef __attribute__((ext_vector_type(8))) unsigned short ushort8;
typedef __attribute__((ext_vector_type(4))) float f32x4;

#define SDIM 48
#define SS   (48*48)
#define SSS  (48*48*48)
#define CIN  120
#define CIP  128
#define NCO  24
#define ZP   52
#define NTAP 125

#define WP_USHORTS (4*25*5*32*32)              // 512000
#define WP_BYTES   ((size_t)WP_USHORTS*2)
#define XT_USHORTS ((size_t)2*48*48*ZP*CIP)
#define XT_BYTES   (XT_USHORTS*2)
#define WTOT_F32   (NCO*CIN*NTAP)

#define APITCH 40                 // ushorts per zp-row: 32 ci + 8 pad = 80 B
#define A_USHORTS (8*52*APITCH)   // 16640 ushorts = 33,280 B

__device__ __forceinline__ unsigned short f2bf(float f){
    unsigned u = __float_as_uint(f);
    u = (u + 0x7FFFu + ((u >> 16) & 1u)) >> 16;
    return (unsigned short)u;
}

// ---------------- MFMA path ----------------

// x[b][ci][X][Y][Z] f32 -> xt[b][ix][iy][zp][ci] bf16 (zp=z+2 halo, ci pad 128)
// LDS-tiled: coalesced z-major reads, transpose in LDS, coalesced ci-major writes
__global__ __launch_bounds__(256)
void transpose_x(const float* __restrict__ x, unsigned short* __restrict__ xt)
{
    __shared__ unsigned short sm[CIN*50];   // pitch 50 (odd-ish) -> conflict-free
    int bid = blockIdx.x;
    const int iy = bid % 48; bid /= 48;
    const int ix = bid % 48;
    const int b  = bid / 48;
    const int tid = threadIdx.x;

    const float* __restrict__ src = x + (size_t)b*CIN*SSS + ((size_t)ix*48 + iy)*48;
    for (int idx = tid; idx < CIN*48; idx += 256) {
        int ci = idx / 48, z = idx - ci*48;
        sm[ci*50 + z] = f2bf(src[(size_t)ci*SSS + z]);
    }
    __syncthreads();
    unsigned short* __restrict__ dst = xt + (((size_t)(b*48 + ix)*48) + iy)*ZP*CIP;
    for (int odx = tid; odx < ZP*CIP; odx += 256) {
        int zp = odx >> 7, ci = odx & 127;
        int z = zp - 2;
        unsigned short v = 0;
        if (ci < CIN && (unsigned)z < 48u) v = sm[ci*50 + z];
        dst[odx] = v;
    }
}

// w[co][ci][dx][dy][dz] f32 -> wp[cc][t][dz][co 32][cik 32] bf16 (zero-padded)
__global__ __launch_bounds__(256)
void repack_w_bf16(const float* __restrict__ w, unsigned short* __restrict__ wp)
{
    int idx = blockIdx.x*256 + threadIdx.x;
    if (idx >= WP_USHORTS) return;
    int cik = idx & 31;
    int co  = (idx >> 5) & 31;
    int dz  = (idx >> 10) % 5;
    int t   = (idx / 5120) % 25;
    int cc  = idx / 128000;
    int ci  = cc*32 + cik;
    float v = 0.f;
    if (co < NCO && ci < CIN)
        v = w[(size_t)(co*CIN + ci)*NTAP + t*5 + dz];
    wp[idx] = f2bf(v);
}

#define MFMA16(a,b,c) __builtin_amdgcn_mfma_f32_16x16x32_bf16(a,b,c,0,0,0)

__global__ __launch_bounds__(256, 4)
void conv_mfma(const unsigned short* __restrict__ xt,
               const unsigned short* __restrict__ wp,
               const float* __restrict__ x,
               float* __restrict__ out)
{
    __shared__ __align__(16) unsigned short As[A_USHORTS];   // 33,280 B; gl unioned

    // bijective XCD swizzle: 1152 blocks = 8 XCDs x 144 contiguous logical ids
    int bid = (blockIdx.x & 7) * 144 + (blockIdx.x >> 3);
    const int oyq = bid % 12; bid /= 12;
    const int ox = bid % 48;
    const int b  = bid / 48;

    const int tid = threadIdx.x;
    const int wave = tid >> 6, lane = tid & 63;
    const int l15 = lane & 15, l4 = lane >> 4;
    const int iy0 = oyq*4 - 2;

    // staging descriptors: 1664 chunks of 16B (8 iy x 52 zp x 4 slots)
    int goff[7], loff[7];
    bool gok[7];
#pragma unroll
    for (int k = 0; k < 7; ++k) {
        int i = tid + k*256;
        int r = i >> 2, slot = i & 3;
        int iyl = r / 52, zp = r - iyl*52;
        int iy = iy0 + iyl;
        gok[k]  = (i < 1664) && ((unsigned)iy < 48u);
        goff[k] = (iy*52 + zp)*CIP + slot*8;
        loff[k] = r*APITCH + slot*8;
    }

    f32x4 acc00={0,0,0,0}, acc01={0,0,0,0};
    f32x4 acc10={0,0,0,0}, acc11={0,0,0,0};
    f32x4 acc20={0,0,0,0}, acc21={0,0,0,0};

    for (int cc = 0; cc < 4; ++cc) {
      const unsigned short* __restrict__ wcc = wp + (size_t)cc*25*5120 + l15*32 + l4*8;
#pragma unroll 1
      for (int dx = 0; dx < 5; ++dx) {
        const int ix = ox + dx - 2;
        if ((unsigned)ix >= 48u) continue;    // block-uniform
        const unsigned short* __restrict__ gbase =
            xt + ((size_t)(b*48 + ix)*48)*ZP*CIP + cc*32;

        ushort8 stg[7];
        const ushort8 zv = {0,0,0,0,0,0,0,0};
#pragma unroll
        for (int k = 0; k < 7; ++k)
            stg[k] = gok[k] ? *(const ushort8*)(gbase + goff[k]) : zv;

        __syncthreads();                      // previous compute done
#pragma unroll
        for (int k = 0; k < 6; ++k)
            *(ushort8*)(As + loff[k]) = stg[k];
        if (tid < 128) *(ushort8*)(As + loff[6]) = stg[6];
        __syncthreads();

        const unsigned short* __restrict__ wdx = wcc + (size_t)dx*5*5120;
#pragma unroll 1
        for (int dy = 0; dy < 5; ++dy) {      // zero-filled rows make all dy valid
            const unsigned short* __restrict__ wt = wdx + dy*5120;
            const unsigned short* __restrict__ ar = As + (wave + dy)*52*APITCH + l4*8;
#pragma unroll
            for (int dz = 0; dz < 5; ++dz) {
                short8 b0 = *(const short8*)(wt + dz*1024);
                short8 b1 = *(const short8*)(wt + dz*1024 + 512);
                short8 a0 = *(const short8*)(ar + (l15 + dz     )*APITCH);
                short8 a1 = *(const short8*)(ar + (l15 + dz + 16)*APITCH);
                short8 a2 = *(const short8*)(ar + (l15 + dz + 32)*APITCH);
                acc00 = MFMA16(a0,b0,acc00);  acc01 = MFMA16(a0,b1,acc01);
                acc10 = MFMA16(a1,b0,acc10);  acc11 = MFMA16(a1,b1,acc11);
                acc20 = MFMA16(a2,b0,acc20);  acc21 = MFMA16(a2,b1,acc21);
            }
        }
      }
    }

    __syncthreads();                          // As -> gl reuse
    float* gl = (float*)As;                   // 192*24 f32 = 18,432 B < 33,280

    // C/D: col = lane&15 (co in tile), row = (lane>>4)*4 + r (z in 16-tile)
#pragma unroll
    for (int nt = 0; nt < 2; ++nt) {
        const int co = nt*16 + l15;
        if (co < NCO) {
            const f32x4 a0 = nt ? acc01 : acc00;
            const f32x4 a1 = nt ? acc11 : acc10;
            const f32x4 a2 = nt ? acc21 : acc20;
#pragma unroll
            for (int r = 0; r < 4; ++r) {
                int z0 = l4*4 + r;
                gl[(wave*48 + z0     )*NCO + co] = 1.f / (1.f + __expf(-a0[r]));
                gl[(wave*48 + z0 + 16)*NCO + co] = 1.f / (1.f + __expf(-a1[r]));
                gl[(wave*48 + z0 + 32)*NCO + co] = 1.f / (1.f + __expf(-a2[r]));
            }
        }
    }
    __syncthreads();

    // epilogue: 384 items = (point 192) x (channel-half 2), fp32 x re-read
    for (int i = tid; i < 384; i += 256) {
        const int p = i % 192;
        const int half = i / 192;
        const int z = p % 48, oyl = p / 48;
        const int oy2 = oyq*4 + oyl;
        const size_t sp = ((size_t)ox*48 + oy2)*48 + z;
        const float* __restrict__ xsp = x   + (size_t)b*CIN*SSS + sp;
        float*       __restrict__ osp = out + (size_t)b*CIN*SSS + sp;
        const float* __restrict__ gp = gl + p*NCO;
        for (int c = half*60; c < half*60 + 60; ++c) {
            float v = xsp[(size_t)c*SSS];
            float o;
            if (c < 32)       o = v > 0.f ? v : 0.f;
            else if (c < 80)  o = v * gp[(c - 32) / 3];
            else              o = v * gp[16 + (c - 80) / 5];
            osp[(size_t)c*SSS] = o;
        }
    }
}

// ---------------- fallback paths (verified rounds 1-2) ----------------

__global__ __launch_bounds__(256)
void repack_w_f32(const float* __restrict__ w, float* __restrict__ wpf)
{
    int idx = blockIdx.x * 256 + threadIdx.x;
    if (idx >= WTOT_F32) return;
    int co = idx % NCO;
    int t  = idx / NCO;
    wpf[idx] = w[co * (CIN * NTAP) + t];
}

__global__ __launch_bounds__(128)
void gated_act_f32(const float* __restrict__ x,
                   const float* __restrict__ wpf,
                   float* __restrict__ out)
{
    const int gid = blockIdx.x * 128 + threadIdx.x;
    const int oz = gid % SDIM;
    int r = gid / SDIM;
    const int oy = r % SDIM; r /= SDIM;
    const int ox = r % SDIM;
    const int b  = r / SDIM;

    const float* __restrict__ xb = x + (size_t)b * CIN * SSS;
    float acc[NCO];
#pragma unroll
    for (int i = 0; i < NCO; ++i) acc[i] = 0.f;

    int izc[5]; bool okz[5];
#pragma unroll
    for (int dz = 0; dz < 5; ++dz) {
        int iz = oz + dz - 2;
        okz[dz] = (unsigned)iz < (unsigned)SDIM;
        izc[dz] = okz[dz] ? iz : 0;
    }
    for (int ci = 0; ci < CIN; ++ci) {
        const float* __restrict__ xc = xb + (size_t)ci * SSS;
        const float* __restrict__ wc = wpf + ci * (NTAP * NCO);
#pragma unroll 1
        for (int dx = 0; dx < 5; ++dx) {
            const int ix = ox + dx - 2;
            const bool okx = (unsigned)ix < (unsigned)SDIM;
            const int ixc = okx ? ix : 0;
#pragma unroll 1
            for (int dy = 0; dy < 5; ++dy) {
                const int iy = oy + dy - 2;
                const bool oky = (unsigned)iy < (unsigned)SDIM;
                const int iyc = oky ? iy : 0;
                const bool okxy = okx && oky;
                const float* __restrict__ xrow = xc + ixc * SS + iyc * SDIM;
                float xv[5];
#pragma unroll
                for (int dz = 0; dz < 5; ++dz) {
                    float v = xrow[izc[dz]];
                    xv[dz] = (okxy && okz[dz]) ? v : 0.f;
                }
                const float* __restrict__ wr = wc + (dx * 25 + dy * 5) * NCO;
#pragma unroll
                for (int dz = 0; dz < 5; ++dz) {
                    const float v = xv[dz];
#pragma unroll
                    for (int co = 0; co < NCO; ++co)
                        acc[co] = fmaf(v, wr[dz * NCO + co], acc[co]);
                }
            }
        }
    }
    float g[NCO];
#pragma unroll
    for (int co = 0; co < NCO; ++co)
        g[co] = 1.f / (1.f + __expf(-acc[co]));

    const size_t sbase = (size_t)b * CIN * SSS + ox * SS + oy * SDIM + oz;
    float* __restrict__ ob = out + sbase;
    const float* __restrict__ xs = x + sbase;
#pragma unroll
    for (int c = 0; c < 32; ++c) {
        float v = xs[(size_t)c * SSS];
        ob[(size_t)c * SSS] = v > 0.f ? v : 0.f;
    }
#pragma unroll
    for (int m = 0; m < 16; ++m) {
        const float gv = g[m];
#pragma unroll
        for (int k = 0; k < 3; ++k) {
            const int c = 32 + m * 3 + k;
            ob[(size_t)c * SSS] = xs[(size_t)c * SSS] * gv;
        }
    }
#pragma unroll
    for (int m = 0; m < 8; ++m) {
        const float gv = g[16 + m];
#pragma unroll
        for (int k = 0; k < 5; ++k) {
            const int c = 80 + m * 5 + k;
            ob[(size_t)c * SSS] = xs[(size_t)c * SSS] * gv;
        }
    }
}

extern "C" void kernel_launch(void* const* d_in, const int* in_sizes, int n_in,
                              void* d_out, int out_size, void* d_ws, size_t ws_size,
                              hipStream_t stream)
{
    const float* x = (const float*)d_in[0];
    const float* w = (const float*)d_in[1];
    float* out = (float*)d_out;

    if (ws_size >= WP_BYTES + XT_BYTES) {
        unsigned short* wp  = (unsigned short*)d_ws;
        unsigned short* xtb = (unsigned short*)((char*)d_ws + WP_BYTES);
        hipLaunchKernelGGL(repack_w_bf16, dim3((WP_USHORTS + 255) / 256), dim3(256),
                           0, stream, w, wp);
        hipLaunchKernelGGL(transpose_x, dim3(2*48*48), dim3(256), 0, stream, x, xtb);
        hipLaunchKernelGGL(conv_mfma, dim3(2*48*12), dim3(256), 0, stream,
                           xtb, wp, x, out);
    } else if (ws_size >= (size_t)WTOT_F32 * 4) {
        float* wpf = (float*)d_ws;
        hipLaunchKernelGGL(repack_w_f32, dim3((WTOT_F32 + 255) / 256), dim3(256),
                           0, stream, w, wpf);
        hipLaunchKernelGGL(gated_act_f32, dim3(2*SSS/128), dim3(128), 0, stream,
                           x, wpf, out);
    }
}

// Round 6
// 472.890 us; speedup vs baseline: 13.6554x; 1.0243x over previous
//
#include <hip/hip_runtime.h>

typedef __attribute__((ext_vector_type(8))) short short8;
typedef __attribute__((ext_vector_type(8))) unsigned short ushort8;
typedef __attribute__((ext_vector_type(4))) float f32x4;

#define SDIM 48
#define SS   (48*48)
#define SSS  (48*48*48)
#define CIN  120
#define CIP  128
#define NCO  24
#define ZP   52
#define NTAP 125

#define WP_USHORTS (4*25*5*32*32)              // 512000
#define WP_BYTES   ((size_t)WP_USHORTS*2)
#define XT_USHORTS ((size_t)2*48*48*ZP*CIP)
#define XT_BYTES   (XT_USHORTS*2)
#define WTOT_F32   (NCO*CIN*NTAP)

// LDS A-tile: [iy 8][slot 4][zp 52][8 ushorts]  (slot-major per iy => reads are
// lane-contiguous 16B chunks within each 16-lane group = m134 conflict-free baseline)
#define AP_SLOT 416                 // 52*8 ushorts
#define AP_IY   (4*AP_SLOT)         // 1664 ushorts
#define ABUF    (8*AP_IY)           // 13312 ushorts = 26,624 B
#define LDS_USH (2*ABUF)            // 53,248 B (double buffer), < 64KB static limit

__device__ __forceinline__ unsigned short f2bf(float f){
    unsigned u = __float_as_uint(f);
    u = (u + 0x7FFFu + ((u >> 16) & 1u)) >> 16;
    return (unsigned short)u;
}

// ---------------- MFMA path ----------------

// x[b][ci][X][Y][Z] f32 -> xt[b][ix][iy][zp][ci] bf16 (zp=z+2 halo, ci pad 128)
__global__ __launch_bounds__(256)
void transpose_x(const float* __restrict__ x, unsigned short* __restrict__ xt)
{
    __shared__ unsigned short sm[CIN*50];
    int bid = blockIdx.x;
    const int iy = bid % 48; bid /= 48;
    const int ix = bid % 48;
    const int b  = bid / 48;
    const int tid = threadIdx.x;

    const float* __restrict__ src = x + (size_t)b*CIN*SSS + ((size_t)ix*48 + iy)*48;
    for (int idx = tid; idx < CIN*48; idx += 256) {
        int ci = idx / 48, z = idx - ci*48;
        sm[ci*50 + z] = f2bf(src[(size_t)ci*SSS + z]);
    }
    __syncthreads();
    unsigned short* __restrict__ dst = xt + (((size_t)(b*48 + ix)*48) + iy)*ZP*CIP;
    for (int odx = tid; odx < ZP*CIP; odx += 256) {
        int zp = odx >> 7, ci = odx & 127;
        int z = zp - 2;
        unsigned short v = 0;
        if (ci < CIN && (unsigned)z < 48u) v = sm[ci*50 + z];
        dst[odx] = v;
    }
}

// w[co][ci][dx][dy][dz] f32 -> wp[cc][t][dz][co 32][cik 32] bf16 (zero-padded)
__global__ __launch_bounds__(256)
void repack_w_bf16(const float* __restrict__ w, unsigned short* __restrict__ wp)
{
    int idx = blockIdx.x*256 + threadIdx.x;
    if (idx >= WP_USHORTS) return;
    int cik = idx & 31;
    int co  = (idx >> 5) & 31;
    int dz  = (idx >> 10) % 5;
    int t   = (idx / 5120) % 25;
    int cc  = idx / 128000;
    int ci  = cc*32 + cik;
    float v = 0.f;
    if (co < NCO && ci < CIN)
        v = w[(size_t)(co*CIN + ci)*NTAP + t*5 + dz];
    wp[idx] = f2bf(v);
}

#define MFMA16(a,b,c) __builtin_amdgcn_mfma_f32_16x16x32_bf16(a,b,c,0,0,0)

__global__ __launch_bounds__(256, 3)
void conv_mfma(const unsigned short* __restrict__ xt,
               const unsigned short* __restrict__ wp,
               const float* __restrict__ x,
               float* __restrict__ out)
{
    __shared__ __align__(16) unsigned short As[LDS_USH];

    // bijective XCD swizzle: 1152 blocks = 8 XCDs x 144 contiguous logical ids
    int bid = (blockIdx.x & 7) * 144 + (blockIdx.x >> 3);
    const int oyq = bid % 12; bid /= 12;
    const int ox = bid % 48;
    const int b  = bid / 48;

    const int tid = threadIdx.x;
    const int wave = tid >> 6, lane = tid & 63;
    const int l15 = lane & 15, l4 = lane >> 4;
    const int iy0 = oyq*4 - 2;

    // valid dx range (block-uniform, contiguous): ix = ox+dx-2 in [0,48)
    const int dxlo = (ox < 2) ? (2 - ox) : 0;
    const int dxhi = (ox > 45) ? (47 - ox + 2) : 4;     // min(4, 49-ox)
    const int ndx  = dxhi - dxlo + 1;

    // staging descriptors: 1664 chunks = (8 iy x 52 zp) x 4 slots
    int goff[7], loff[7];
    bool gok[7];
#pragma unroll
    for (int k = 0; k < 7; ++k) {
        int i = tid + k*256;
        int r = i >> 2, slot = i & 3;
        int iyl = r / 52, zp = r - iyl*52;
        int iy = iy0 + iyl;
        gok[k]  = (i < 1664) && ((unsigned)iy < 48u);
        goff[k] = (iy*52 + zp)*CIP + slot*8;
        loff[k] = iyl*AP_IY + slot*AP_SLOT + zp*8;
    }
    const bool lok6 = (tid < 128);

    f32x4 acc00={0,0,0,0}, acc01={0,0,0,0};
    f32x4 acc10={0,0,0,0}, acc11={0,0,0,0};
    f32x4 acc20={0,0,0,0}, acc21={0,0,0,0};

    const ushort8 zv = {0,0,0,0,0,0,0,0};
    ushort8 stg[7];

    // prologue: load (cc=0, dx=dxlo)
    {
        const unsigned short* __restrict__ gbase =
            xt + ((size_t)(b*48 + ox + dxlo - 2)*48)*ZP*CIP;
#pragma unroll
        for (int k = 0; k < 7; ++k)
            stg[k] = gok[k] ? *(const ushort8*)(gbase + goff[k]) : zv;
    }

    int p = 0;
#pragma unroll 1
    for (int cc = 0; cc < 4; ++cc) {
#pragma unroll 1
      for (int dxi = 0; dxi < ndx; ++dxi) {
        const int dx = dxlo + dxi;
        unsigned short* __restrict__ buf = As + p*ABUF;

        // write staged regs -> buf[p]   (stg holds this step's tile)
#pragma unroll
        for (int k = 0; k < 6; ++k)
            *(ushort8*)(buf + loff[k]) = stg[k];
        if (lok6) *(ushort8*)(buf + loff[6]) = stg[6];
        __syncthreads();   // writes visible; also fences vi-1 reads vs vi+1 writes

        // prefetch next step's tile (latency hides under compute below)
        {
            const int more = (dxi + 1 < ndx);
            const int cc2 = more ? cc : cc + 1;
            const int dx2 = more ? dx + 1 : dxlo;
            if (cc2 < 4) {
                const unsigned short* __restrict__ gbase =
                    xt + ((size_t)(b*48 + ox + dx2 - 2)*48)*ZP*CIP + cc2*32;
#pragma unroll
                for (int k = 0; k < 7; ++k)
                    stg[k] = gok[k] ? *(const ushort8*)(gbase + goff[k]) : zv;
            }
        }

        // compute from buf[p]
        const unsigned short* __restrict__ wdx =
            wp + (size_t)cc*128000 + (size_t)dx*5*5120 + l15*32 + l4*8;
        const unsigned short* __restrict__ arw = buf + l4*AP_SLOT + l15*8;
#pragma unroll 1
        for (int dy = 0; dy < 5; ++dy) {
            const unsigned short* __restrict__ wt = wdx + dy*5120;
            const unsigned short* __restrict__ ar = arw + (wave + dy)*AP_IY;
#pragma unroll
            for (int dz = 0; dz < 5; ++dz) {
                short8 b0 = *(const short8*)(wt + dz*1024);
                short8 b1 = *(const short8*)(wt + dz*1024 + 512);
                short8 a0 = *(const short8*)(ar + dz*8);          // zp = l15+dz
                short8 a1 = *(const short8*)(ar + dz*8 + 128);    // zp+16
                short8 a2 = *(const short8*)(ar + dz*8 + 256);    // zp+32
                acc00 = MFMA16(a0,b0,acc00);  acc01 = MFMA16(a0,b1,acc01);
                acc10 = MFMA16(a1,b0,acc10);  acc11 = MFMA16(a1,b1,acc11);
                acc20 = MFMA16(a2,b0,acc20);  acc21 = MFMA16(a2,b1,acc21);
            }
        }
        p ^= 1;
      }
    }

    __syncthreads();                          // As -> gl reuse
    float* gl = (float*)As;                   // 192*24 f32 = 18,432 B < 53,248

    // C/D: col = lane&15 (co in tile), row = (lane>>4)*4 + r (z in 16-tile)
#pragma unroll
    for (int nt = 0; nt < 2; ++nt) {
        const int co = nt*16 + l15;
        if (co < NCO) {
            const f32x4 a0 = nt ? acc01 : acc00;
            const f32x4 a1 = nt ? acc11 : acc10;
            const f32x4 a2 = nt ? acc21 : acc20;
#pragma unroll
            for (int r = 0; r < 4; ++r) {
                int z0 = l4*4 + r;
                gl[(wave*48 + z0     )*NCO + co] = 1.f / (1.f + __expf(-a0[r]));
                gl[(wave*48 + z0 + 16)*NCO + co] = 1.f / (1.f + __expf(-a1[r]));
                gl[(wave*48 + z0 + 32)*NCO + co] = 1.f / (1.f + __expf(-a2[r]));
            }
        }
    }
    __syncthreads();

    // epilogue: 384 items = (point 192) x (channel-half 2), fp32 x re-read
    for (int i = tid; i < 384; i += 256) {
        const int pnt = i % 192;
        const int half = i / 192;
        const int z = pnt % 48, oyl = pnt / 48;
        const int oy2 = oyq*4 + oyl;
        const size_t sp = ((size_t)ox*48 + oy2)*48 + z;
        const float* __restrict__ xsp = x   + (size_t)b*CIN*SSS + sp;
        float*       __restrict__ osp = out + (size_t)b*CIN*SSS + sp;
        const float* __restrict__ gp = gl + pnt*NCO;
        for (int c = half*60; c < half*60 + 60; ++c) {
            float v = xsp[(size_t)c*SSS];
            float o;
            if (c < 32)       o = v > 0.f ? v : 0.f;
            else if (c < 80)  o = v * gp[(c - 32) / 3];
            else              o = v * gp[16 + (c - 80) / 5];
            osp[(size_t)c*SSS] = o;
        }
    }
}

// ---------------- fallback paths (verified rounds 1-2) ----------------

__global__ __launch_bounds__(256)
void repack_w_f32(const float* __restrict__ w, float* __restrict__ wpf)
{
    int idx = blockIdx.x * 256 + threadIdx.x;
    if (idx >= WTOT_F32) return;
    int co = idx % NCO;
    int t  = idx / NCO;
    wpf[idx] = w[co * (CIN * NTAP) + t];
}

__global__ __launch_bounds__(128)
void gated_act_f32(const float* __restrict__ x,
                   const float* __restrict__ wpf,
                   float* __restrict__ out)
{
    const int gid = blockIdx.x * 128 + threadIdx.x;
    const int oz = gid % SDIM;
    int r = gid / SDIM;
    const int oy = r % SDIM; r /= SDIM;
    const int ox = r % SDIM;
    const int b  = r / SDIM;

    const float* __restrict__ xb = x + (size_t)b * CIN * SSS;
    float acc[NCO];
#pragma unroll
    for (int i = 0; i < NCO; ++i) acc[i] = 0.f;

    int izc[5]; bool okz[5];
#pragma unroll
    for (int dz = 0; dz < 5; ++dz) {
        int iz = oz + dz - 2;
        okz[dz] = (unsigned)iz < (unsigned)SDIM;
        izc[dz] = okz[dz] ? iz : 0;
    }
    for (int ci = 0; ci < CIN; ++ci) {
        const float* __restrict__ xc = xb + (size_t)ci * SSS;
        const float* __restrict__ wc = wpf + ci * (NTAP * NCO);
#pragma unroll 1
        for (int dx = 0; dx < 5; ++dx) {
            const int ix = ox + dx - 2;
            const bool okx = (unsigned)ix < (unsigned)SDIM;
            const int ixc = okx ? ix : 0;
#pragma unroll 1
            for (int dy = 0; dy < 5; ++dy) {
                const int iy = oy + dy - 2;
                const bool oky = (unsigned)iy < (unsigned)SDIM;
                const int iyc = oky ? iy : 0;
                const bool okxy = okx && oky;
                const float* __restrict__ xrow = xc + ixc * SS + iyc * SDIM;
                float xv[5];
#pragma unroll
                for (int dz = 0; dz < 5; ++dz) {
                    float v = xrow[izc[dz]];
                    xv[dz] = (okxy && okz[dz]) ? v : 0.f;
                }
                const float* __restrict__ wr = wc + (dx * 25 + dy * 5) * NCO;
#pragma unroll
                for (int dz = 0; dz < 5; ++dz) {
                    const float v = xv[dz];
#pragma unroll
                    for (int co = 0; co < NCO; ++co)
                        acc[co] = fmaf(v, wr[dz * NCO + co], acc[co]);
                }
            }
        }
    }
    float g[NCO];
#pragma unroll
    for (int co = 0; co < NCO; ++co)
        g[co] = 1.f / (1.f + __expf(-acc[co]));

    const size_t sbase = (size_t)b * CIN * SSS + ox * SS + oy * SDIM + oz;
    float* __restrict__ ob = out + sbase;
    const float* __restrict__ xs = x + sbase;
#pragma unroll
    for (int c = 0; c < 32; ++c) {
        float v = xs[(size_t)c * SSS];
        ob[(size_t)c * SSS] = v > 0.f ? v : 0.f;
    }
#pragma unroll
    for (int m = 0; m < 16; ++m) {
        const float gv = g[m];
#pragma unroll
        for (int k = 0; k < 3; ++k) {
            const int c = 32 + m * 3 + k;
            ob[(size_t)c * SSS] = xs[(size_t)c * SSS] * gv;
        }
    }
#pragma unroll
    for (int m = 0; m < 8; ++m) {
        const float gv = g[16 + m];
#pragma unroll
        for (int k = 0; k < 5; ++k) {
            const int c = 80 + m * 5 + k;
            ob[(size_t)c * SSS] = xs[(size_t)c * SSS] * gv;
        }
    }
}

extern "C" void kernel_launch(void* const* d_in, const int* in_sizes, int n_in,
                              void* d_out, int out_size, void* d_ws, size_t ws_size,
                              hipStream_t stream)
{
    const float* x = (const float*)d_in[0];
    const float* w = (const float*)d_in[1];
    float* out = (float*)d_out;

    if (ws_size >= WP_BYTES + XT_BYTES) {
        unsigned short* wp  = (unsigned short*)d_ws;
        unsigned short* xtb = (unsigned short*)((char*)d_ws + WP_BYTES);
        hipLaunchKernelGGL(repack_w_bf16, dim3((WP_USHORTS + 255) / 256), dim3(256),
                           0, stream, w, wp);
        hipLaunchKernelGGL(transpose_x, dim3(2*48*48), dim3(256), 0, stream, x, xtb);
        hipLaunchKernelGGL(conv_mfma, dim3(2*48*12), dim3(256), 0, stream,
                           xtb, wp, x, out);
    } else if (ws_size >= (size_t)WTOT_F32 * 4) {
        float* wpf = (float*)d_ws;
        hipLaunchKernelGGL(repack_w_f32, dim3((WTOT_F32 + 255) / 256), dim3(256),
                           0, stream, w, wpf);
        hipLaunchKernelGGL(gated_act_f32, dim3(2*SSS/128), dim3(128), 0, stream,
                           x, wpf, out);
    }
}